// Round 4
// baseline (706.379 us; speedup 1.0000x reference)
//
#include <hip/hip_runtime.h>
#include <math.h>

#define N_TOK 16384
#define DDIM  4096
#define NEXP  64
#define TM    32            // tokens per block
#define BK    64            // K chunk
#define LSTR  68            // LDS row stride (floats): 16B-aligned rows, conflict-free
#define TAU   2e-3f         // near-tie flag threshold (fp32 accum error ~3e-6; ~600x margin)

__global__ __launch_bounds__(256) void topk_gate_kernel(
    const float* __restrict__ x, const float* __restrict__ W,
    float* __restrict__ out)
{
    __shared__ float  Xs[TM * LSTR];         // [tok][k]
    __shared__ float  Ws[BK * LSTR];         // [k][e]  (transposed in staging)
    __shared__ float  Lg[TM * LSTR];         // logits [tok][e]
    __shared__ int    top_i[TM * 2];
    __shared__ float  top_w[TM * 2];
    __shared__ int    nflag;
    __shared__ int    flist[TM];
    __shared__ double red[256];
    __shared__ double lgd[NEXP];
    __shared__ int    rbi[2];
    __shared__ float  rbw[2];

    const int tid = threadIdx.x;
    const int block_tok = blockIdx.x * TM;

    // compute-phase thread tile: 2 tokens x 4 experts
    const int eg = tid & 15;
    const int tg = tid >> 4;
    const int t0 = tg * 2;
    const int e0 = eg * 4;

    // staging mappings
    const int xs_tok = tid >> 3, xs_kq = tid & 7;   // X: 2 float4/thread
    const int ws_e   = tid >> 2, ws_kq = tid & 3;   // W: 4 float4/thread (transposing store)

    const float* xg = x + (size_t)(block_tok + xs_tok) * DDIM + xs_kq * 4;
    const float* wg = W + (size_t)ws_e * DDIM;      // BUGFIX: no ws_kq*4 here (was double-counted)

    float acc[2][4] = {{0.f,0.f,0.f,0.f},{0.f,0.f,0.f,0.f}};

    for (int kb = 0; kb < DDIM; kb += BK) {
        float4 xv0 = *(const float4*)(xg + kb);
        float4 xv1 = *(const float4*)(xg + kb + 32);
        *(float4*)(&Xs[xs_tok * LSTR + xs_kq * 4])      = xv0;
        *(float4*)(&Xs[xs_tok * LSTR + xs_kq * 4 + 32]) = xv1;
        #pragma unroll
        for (int i = 0; i < 4; ++i) {
            int kbase = ws_kq * 4 + 16 * i;
            float4 wv = *(const float4*)(wg + kb + kbase);
            Ws[(kbase + 0) * LSTR + ws_e] = wv.x;
            Ws[(kbase + 1) * LSTR + ws_e] = wv.y;
            Ws[(kbase + 2) * LSTR + ws_e] = wv.z;
            Ws[(kbase + 3) * LSTR + ws_e] = wv.w;
        }
        __syncthreads();

        #pragma unroll
        for (int kk = 0; kk < BK; kk += 4) {
            float4 xa = *(const float4*)(&Xs[(t0 + 0) * LSTR + kk]);
            float4 xb = *(const float4*)(&Xs[(t0 + 1) * LSTR + kk]);
            const float* xap = (const float*)&xa;
            const float* xbp = (const float*)&xb;
            #pragma unroll
            for (int i = 0; i < 4; ++i) {
                float4 wf = *(const float4*)(&Ws[(kk + i) * LSTR + e0]);
                const float* wp = (const float*)&wf;
                float va = xap[i], vb = xbp[i];
                #pragma unroll
                for (int j = 0; j < 4; ++j) {
                    acc[0][j] = fmaf(va, wp[j], acc[0][j]);
                    acc[1][j] = fmaf(vb, wp[j], acc[1][j]);
                }
            }
        }
        __syncthreads();
    }

    #pragma unroll
    for (int t = 0; t < 2; ++t)
        #pragma unroll
        for (int j = 0; j < 4; ++j)
            Lg[(t0 + t) * LSTR + e0 + j] = acc[t][j];
    if (tid == 0) nflag = 0;
    __syncthreads();

    // ---- top-3 scan + 2-way softmax + near-tie flagging ----
    if (tid < TM) {
        const float* row = &Lg[tid * LSTR];
        float m1 = -INFINITY, m2 = -INFINITY, m3 = -INFINITY;
        int i1 = 0, i2 = 0;
        for (int e = 0; e < NEXP; ++e) {
            float v = row[e];
            if (v > m1)      { m3 = m2; m2 = m1; i2 = i1; m1 = v; i1 = e; }
            else if (v > m2) { m3 = m2; m2 = v; i2 = e; }
            else if (v > m3) { m3 = v; }
        }
        float d  = expf(m2 - m1);
        float rn = 1.0f / (1.0f + d);
        top_i[tid * 2 + 0] = i1;  top_i[tid * 2 + 1] = i2;
        top_w[tid * 2 + 0] = rn;  top_w[tid * 2 + 1] = d * rn;
        float2* oi = (float2*)(out + (size_t)N_TOK * NEXP);
        oi[block_tok + tid] = make_float2((float)i1, (float)i2);
        if ((m1 - m2 < TAU) || (m2 - m3 < TAU)) {
            int p = atomicAdd(&nflag, 1);
            flist[p] = tid;
        }
    }
    __syncthreads();

    // ---- dense weight scatter: 32 tokens x 64 experts, float4 coalesced ----
    float4* ow = (float4*)(out + (size_t)block_tok * NEXP);
    #pragma unroll
    for (int jj = 0; jj < 2; ++jj) {
        int flat = tid + jj * 256;
        int tok  = flat >> 4;
        int e4   = (flat & 15) * 4;
        int a1 = top_i[tok * 2], a2 = top_i[tok * 2 + 1];
        float v1 = top_w[tok * 2], v2 = top_w[tok * 2 + 1];
        float4 v; float* vp = (float*)&v;
        #pragma unroll
        for (int q = 0; q < 4; ++q) {
            int e = e4 + q;
            vp[q] = (e == a1) ? v1 : ((e == a2) ? v2 : 0.0f);
        }
        ow[flat] = v;
    }
    __syncthreads();

    // ---- in-block fp64 re-resolution of flagged tokens (typically 0-1 per block) ----
    const int fn = nflag;
    for (int f = 0; f < fn; ++f) {
        const int tok = block_tok + flist[f];
        const int e = tid & 63, q = tid >> 6;           // expert, k-quarter
        const float* wr = W + (size_t)e * DDIM + q * (DDIM / 4);
        const float* xr = x + (size_t)tok * DDIM + q * (DDIM / 4);
        double p = 0.0;
        for (int k = 0; k < DDIM / 4; k += 4) {
            float4 wv = *(const float4*)(wr + k);       // per-lane distinct row
            float4 xv = *(const float4*)(xr + k);       // wave-uniform -> L1 broadcast
            p += (double)xv.x * (double)wv.x;
            p += (double)xv.y * (double)wv.y;
            p += (double)xv.z * (double)wv.z;
            p += (double)xv.w * (double)wv.w;
        }
        red[tid] = p;
        __syncthreads();
        if (tid < 64) lgd[tid] = red[tid] + red[tid + 64] + red[tid + 128] + red[tid + 192];
        __syncthreads();

        if (tid == 0) {
            double m1 = -INFINITY, m2 = -INFINITY;
            int i1 = 0, i2 = 0;
            for (int ee = 0; ee < NEXP; ++ee) {
                double v = lgd[ee];
                if (v > m1)      { m2 = m1; i2 = i1; m1 = v; i1 = ee; }
                else if (v > m2) { m2 = v; i2 = ee; }
            }
            double d  = exp(m2 - m1);
            double rn = 1.0 / (1.0 + d);
            rbi[0] = i1; rbi[1] = i2;
            rbw[0] = (float)rn; rbw[1] = (float)(d * rn);
            float2* oi = (float2*)(out + (size_t)N_TOK * NEXP);
            oi[tok] = make_float2((float)i1, (float)i2);
        }
        __syncthreads();

        if (tid < 16) {
            float4 v = make_float4(0.f, 0.f, 0.f, 0.f);
            float* vp = (float*)&v;
            #pragma unroll
            for (int qq = 0; qq < 4; ++qq) {
                int ee = tid * 4 + qq;
                if (ee == rbi[0]) vp[qq] = rbw[0];
                else if (ee == rbi[1]) vp[qq] = rbw[1];
            }
            ((float4*)(out + (size_t)tok * NEXP))[tid] = v;
        }
        __syncthreads();
    }
}

extern "C" void kernel_launch(void* const* d_in, const int* in_sizes, int n_in,
                              void* d_out, int out_size, void* d_ws, size_t ws_size,
                              hipStream_t stream) {
    const float* x = (const float*)d_in[0];   // [16384, 4096] fp32
    const float* W = (const float*)d_in[1];   // [64, 4096] fp32
    float* out = (float*)d_out;               // weights [16384*64] then indices [16384*2]
    (void)in_sizes; (void)n_in; (void)d_ws; (void)ws_size; (void)out_size;

    hipLaunchKernelGGL(topk_gate_kernel, dim3(N_TOK / TM), dim3(256), 0, stream,
                       x, W, out);
}

// Round 5
// 583.361 us; speedup vs baseline: 1.2109x; 1.2109x over previous
//
#include <hip/hip_runtime.h>
#include <math.h>

#define N_TOK 16384
#define DDIM  4096
#define NEXP  64
#define TM    32            // tokens per block
#define KHALF 2048          // K split in two halves, combined in epilogue
#define LSTR  68            // LDS logit row stride
#define TAU   1e-3f         // near-tie refine threshold (split-bf16 noise ~1e-5)

typedef __attribute__((ext_vector_type(8))) short bf16x8;
typedef __attribute__((ext_vector_type(4))) float f32x4;

// Split 8 consecutive fp32 into hi/lo bf16 (truncation split: x = hi + lo + eps,
// |lo| <= 2^-8|x|, |eps| <= 2^-16|x|; eps zero-mean vs random w).
__device__ __forceinline__ void split8(f32x4 v0, f32x4 v1, bf16x8& hi, bf16x8& lo) {
    float f[8];
    *(f32x4*)&f[0] = v0;  *(f32x4*)&f[4] = v1;
    #pragma unroll
    for (int i = 0; i < 8; ++i) {
        unsigned u  = __float_as_uint(f[i]);
        unsigned uh = u & 0xFFFF0000u;
        float    rf = f[i] - __uint_as_float(uh);
        hi[i] = (short)(u >> 16);
        lo[i] = (short)(__float_as_uint(rf) >> 16);
    }
}

__global__ __launch_bounds__(256) void topk_gate_kernel(
    const float* __restrict__ x, const float* __restrict__ W,
    float* __restrict__ out)
{
    __shared__ float  Lgh[2][TM][LSTR];      // per-K-half logits
    __shared__ int    top_i[TM * 2];
    __shared__ float  top_w[TM * 2];
    __shared__ int    nflag;
    __shared__ int    flist[TM];
    __shared__ double red[256];
    __shared__ double lgd[NEXP];
    __shared__ int    rbi[2];
    __shared__ float  rbw[2];

    const int tid  = threadIdx.x;
    const int lane = tid & 63;
    const int w    = tid >> 6;           // wave 0..3
    const int tg   = w & 1;              // token group (16 tokens)
    const int half = w >> 1;             // K half
    const int block_tok = blockIdx.x * TM;

    const int r16  = lane & 15;          // row within 16 (token / expert)
    const int koct = lane >> 4;          // k-octet 0..3

    // A: x[block_tok + tg*16 + r16][half*KHALF + koct*8 + kb + (0..7)]
    const float* xp = x + (size_t)(block_tok + tg * 16 + r16) * DDIM
                        + half * KHALF + koct * 8;
    // B tile t: W[t*16 + r16][half*KHALF + koct*8 + kb + (0..7)]
    const float* wp0 = W + (size_t)r16 * DDIM + half * KHALF + koct * 8;

    f32x4 acc[4];
    #pragma unroll
    for (int t = 0; t < 4; ++t) acc[t] = (f32x4){0.f, 0.f, 0.f, 0.f};

    #pragma unroll 2
    for (int kb = 0; kb < KHALF; kb += 32) {
        f32x4 a0 = *(const f32x4*)(xp + kb);
        f32x4 a1 = *(const f32x4*)(xp + kb + 4);
        bf16x8 ah, al;
        split8(a0, a1, ah, al);
        #pragma unroll
        for (int t = 0; t < 4; ++t) {
            const float* wp = wp0 + (size_t)t * 16 * DDIM + kb;
            f32x4 b0 = *(const f32x4*)(wp);
            f32x4 b1 = *(const f32x4*)(wp + 4);
            bf16x8 bh, bl;
            split8(b0, b1, bh, bl);
            acc[t] = __builtin_amdgcn_mfma_f32_16x16x32_bf16(ah, bh, acc[t], 0, 0, 0);
            acc[t] = __builtin_amdgcn_mfma_f32_16x16x32_bf16(ah, bl, acc[t], 0, 0, 0);
            acc[t] = __builtin_amdgcn_mfma_f32_16x16x32_bf16(al, bh, acc[t], 0, 0, 0);
        }
    }

    // C/D layout (m89-verified): col = lane&15 (expert), row = (lane>>4)*4 + reg (token)
    #pragma unroll
    for (int t = 0; t < 4; ++t)
        #pragma unroll
        for (int r = 0; r < 4; ++r)
            Lgh[half][tg * 16 + koct * 4 + r][t * 16 + r16] = acc[t][r];
    if (tid == 0) nflag = 0;
    __syncthreads();

    // ---- combine halves + top-3 scan + 2-way softmax + near-tie flagging ----
    if (tid < TM) {
        float m1 = -INFINITY, m2 = -INFINITY, m3 = -INFINITY;
        int i1 = 0, i2 = 0;
        for (int e = 0; e < NEXP; ++e) {
            float v = Lgh[0][tid][e] + Lgh[1][tid][e];
            if (v > m1)      { m3 = m2; m2 = m1; i2 = i1; m1 = v; i1 = e; }
            else if (v > m2) { m3 = m2; m2 = v; i2 = e; }
            else if (v > m3) { m3 = v; }
        }
        float d  = expf(m2 - m1);
        float rn = 1.0f / (1.0f + d);
        top_i[tid * 2 + 0] = i1;  top_i[tid * 2 + 1] = i2;
        top_w[tid * 2 + 0] = rn;  top_w[tid * 2 + 1] = d * rn;
        float2* oi = (float2*)(out + (size_t)N_TOK * NEXP);
        oi[block_tok + tid] = make_float2((float)i1, (float)i2);
        if ((m1 - m2 < TAU) || (m2 - m3 < TAU)) {
            int p = atomicAdd(&nflag, 1);
            flist[p] = tid;
        }
    }
    __syncthreads();

    // ---- dense weight scatter: 32 tokens x 64 experts, float4 coalesced ----
    float4* ow = (float4*)(out + (size_t)block_tok * NEXP);
    #pragma unroll
    for (int jj = 0; jj < 2; ++jj) {
        int flat = tid + jj * 256;
        int tok  = flat >> 4;
        int e4   = (flat & 15) * 4;
        int a1 = top_i[tok * 2], a2 = top_i[tok * 2 + 1];
        float v1 = top_w[tok * 2], v2 = top_w[tok * 2 + 1];
        float4 v; float* vp = (float*)&v;
        #pragma unroll
        for (int q = 0; q < 4; ++q) {
            int e = e4 + q;
            vp[q] = (e == a1) ? v1 : ((e == a2) ? v2 : 0.0f);
        }
        ow[flat] = v;
    }
    __syncthreads();

    // ---- in-block fp64 re-resolution of flagged tokens (expected ~0.07/block) ----
    const int fn = nflag;
    for (int f = 0; f < fn; ++f) {
        const int tok = block_tok + flist[f];
        const int e = tid & 63, q = tid >> 6;
        const float* wr = W + (size_t)e * DDIM + q * (DDIM / 4);
        const float* xr = x + (size_t)tok * DDIM + q * (DDIM / 4);
        double p = 0.0;
        for (int k = 0; k < DDIM / 4; k += 4) {
            float4 wv = *(const float4*)(wr + k);
            float4 xv = *(const float4*)(xr + k);
            p += (double)xv.x * (double)wv.x;
            p += (double)xv.y * (double)wv.y;
            p += (double)xv.z * (double)wv.z;
            p += (double)xv.w * (double)wv.w;
        }
        red[tid] = p;
        __syncthreads();
        if (tid < 64) lgd[tid] = red[tid] + red[tid + 64] + red[tid + 128] + red[tid + 192];
        __syncthreads();

        if (tid == 0) {
            double m1 = -INFINITY, m2 = -INFINITY;
            int i1 = 0, i2 = 0;
            for (int ee = 0; ee < NEXP; ++ee) {
                double v = lgd[ee];
                if (v > m1)      { m2 = m1; i2 = i1; m1 = v; i1 = ee; }
                else if (v > m2) { m2 = v; i2 = ee; }
            }
            double d  = exp(m2 - m1);
            double rn = 1.0 / (1.0 + d);
            rbi[0] = i1; rbi[1] = i2;
            rbw[0] = (float)rn; rbw[1] = (float)(d * rn);
            float2* oi = (float2*)(out + (size_t)N_TOK * NEXP);
            oi[tok] = make_float2((float)i1, (float)i2);
        }
        __syncthreads();

        if (tid < 16) {
            float4 v = make_float4(0.f, 0.f, 0.f, 0.f);
            float* vp = (float*)&v;
            #pragma unroll
            for (int qq = 0; qq < 4; ++qq) {
                int ee = tid * 4 + qq;
                if (ee == rbi[0]) vp[qq] = rbw[0];
                else if (ee == rbi[1]) vp[qq] = rbw[1];
            }
            ((float4*)(out + (size_t)tok * NEXP))[tid] = v;
        }
        __syncthreads();
    }
}

extern "C" void kernel_launch(void* const* d_in, const int* in_sizes, int n_in,
                              void* d_out, int out_size, void* d_ws, size_t ws_size,
                              hipStream_t stream) {
    const float* x = (const float*)d_in[0];   // [16384, 4096] fp32
    const float* W = (const float*)d_in[1];   // [64, 4096] fp32
    float* out = (float*)d_out;               // weights [16384*64] then indices [16384*2]
    (void)in_sizes; (void)n_in; (void)d_ws; (void)ws_size; (void)out_size;

    hipLaunchKernelGGL(topk_gate_kernel, dim3(N_TOK / TM), dim3(256), 0, stream,
                       x, W, out);
}